// Round 15
// baseline (364.665 us; speedup 1.0000x reference)
//
#include <hip/hip_runtime.h>
#include <hip/hip_bf16.h>

#define HW 128
#define NPIX (HW * HW)
#define HB 130            // halo-padded activation image width
#define HPIX (HB * HB)
#define ITW 148           // halo-padded transposed-input width (halo 10)
#define EPS 1e-4f

typedef __attribute__((ext_vector_type(16))) float f32x16;
typedef __attribute__((ext_vector_type(4))) float f32x4;
typedef __attribute__((ext_vector_type(2))) float f32x2;
typedef _Float16 f16;
typedef __attribute__((ext_vector_type(8))) _Float16 f16x8;
typedef __attribute__((ext_vector_type(4))) _Float16 f16x4;
typedef __attribute__((ext_vector_type(4))) int i32x4;

__device__ __forceinline__ f32x2 shflx2(f32x2 v, int m) {
  double d = __builtin_bit_cast(double, v);
  d = __shfl_xor(d, m);
  return __builtin_bit_cast(f32x2, d);
}

// ---------------------------------------------------------------------------
__global__ __launch_bounds__(256) void zero_buf(i32x4* __restrict__ p, int n) {
  int i = blockIdx.x * 256 + threadIdx.x;
  if (i < n) p[i] = i32x4{0, 0, 0, 0};
}

// ---------------------------------------------------------------------------
// transpose input NCHW fp32 -> halo-padded [148*148][16] fp32
// ch0 = validity/ones, ch1..3 = input[0..2], ch4..10 = input[3..9], rest 0
// ---------------------------------------------------------------------------
__global__ __launch_bounds__(256) void prep_input_k(
    const float* __restrict__ in, float* __restrict__ itp) {
  int idx = blockIdx.x * 256 + threadIdx.x;
  if (idx >= ITW * ITW) return;
  int py = idx / ITW, px = idx - py * ITW;
  float v[16];
#pragma unroll
  for (int i = 0; i < 16; i++) v[i] = 0.f;
  if (py >= 10 && py < 138 && px >= 10 && px < 138) {
    int p = (py - 10) * HW + (px - 10);
    v[0] = 1.f;
#pragma unroll
    for (int c = 0; c < 10; c++) v[1 + c] = in[c * NPIX + p];
  }
  float4* op = (float4*)(itp + idx * 16);
#pragma unroll
  for (int g = 0; g < 4; g++)
    op[g] = make_float4(v[g * 4], v[g * 4 + 1], v[g * 4 + 2], v[g * 4 + 3]);
}

// ---------------------------------------------------------------------------
// weight repack for 32x32x16 MFMA fragments:
//   wb[L][t][cg][kc][lane][e] (f16), co = cg*32 + (lane&31),
//   ci = kc*16 + (lane>>5)*8 + e  -> one wave A-frag load = contiguous 1KB.
// wmid: 23 layers, cg 0..3 (co pad 128), kc 0..7 (ci pad 128). 16384/tap.
// ---------------------------------------------------------------------------
__global__ __launch_bounds__(256) void pack_wmid_k(
    const float* __restrict__ wm, f16* __restrict__ wb) {
  int idx = blockIdx.x * 256 + threadIdx.x;  // 23*9*16384
  int e = idx & 7;
  int l = (idx >> 3) & 63;
  int kc = (idx >> 9) & 7;
  int cg = (idx >> 12) & 3;
  int tL = idx >> 14;
  int L = tL / 9;
  int t = tL - L * 9;
  int co = cg * 32 + (l & 31);
  int ci = kc * 16 + (l >> 5) * 8 + e;
  float v = 0.f;
  if (co < 100 && ci < 100) v = wm[((L * 100 + co) * 100 + ci) * 9 + t];
  wb[idx] = (f16)v;
}

// wfin [441][100][3][3] f32 -> [9][16cg][8kc][64][8]  (co padded to 512)
__global__ __launch_bounds__(256) void pack_wfin_k(
    const float* __restrict__ wf, f16* __restrict__ wb) {
  int idx = blockIdx.x * 256 + threadIdx.x;  // 9*65536
  int e = idx & 7;
  int l = (idx >> 3) & 63;
  int kc = (idx >> 9) & 7;
  int cg = (idx >> 12) & 15;
  int t = idx >> 16;
  int co = cg * 32 + (l & 31);
  int ci = kc * 16 + (l >> 5) * 8 + e;
  float v = 0.f;
  if (co < 441 && ci < 100) v = wf[(co * 100 + ci) * 9 + t];
  wb[idx] = (f16)v;
}

// ---------------------------------------------------------------------------
// conv0: 10 -> 100 direct fp32, write f16 halo NHWC [HPIX][128]
// ---------------------------------------------------------------------------
__global__ __launch_bounds__(256) void conv0_k(
    const float* __restrict__ in, const float* __restrict__ w0,
    const float* __restrict__ b0, f16* __restrict__ act) {
  const int tx = threadIdx.x & 15, ty = threadIdx.x >> 4;
  const int x = blockIdx.x * 16 + tx, y = blockIdx.y * 16 + ty;
  const int co0 = blockIdx.z * 16;
  const int nco = max(0, min(16, 100 - co0));
  float acc[16];
#pragma unroll
  for (int i = 0; i < 16; i++) acc[i] = (i < nco) ? b0[co0 + i] : 0.f;
  for (int ci = 0; ci < 10; ci++) {
    const float* ip = in + ci * NPIX;
    float v[9];
#pragma unroll
    for (int t = 0; t < 9; t++) {
      int ny = y + t / 3 - 1, nx = x + t % 3 - 1;
      bool ok = ((unsigned)ny < (unsigned)HW) && ((unsigned)nx < (unsigned)HW);
      v[t] = ok ? ip[ny * HW + nx] : 0.f;
    }
    const float* wp = w0 + (co0 * 10 + ci) * 9;
#pragma unroll
    for (int i = 0; i < 16; i++) {
      if (i < nco) {
#pragma unroll
        for (int t = 0; t < 9; t++)
          acc[i] = fmaf(wp[i * 90 + t], v[t], acc[i]);
      }
    }
  }
  f16* op = act + ((y + 1) * HB + (x + 1)) * 128 + co0;
#pragma unroll
  for (int g = 0; g < 4; g++) {
    f16x4 sv;
#pragma unroll
    for (int j = 0; j < 4; j++) sv[j] = (f16)acc[g * 4 + j];
    *(f16x4*)(op + g * 4) = sv;
  }
}

// ---------------------------------------------------------------------------
// implicit-GEMM 3x3 conv, MFMA f16 32x32x16 (2x FLOP per B-fragment vs
// 16x16x32 -> halves LDS-read volume, the measured limiter).
//  - Block = 4 waves; wave owns one co-group of 32 (cg), PX=32 px, PY rows.
//  - B in LDS [(PY+2)][34][16ch] (XOR chunk swizzle), staged once, ONE barrier.
//  - A global->VGPR register dbuf af[2][8kc], next tap issued early.
//  - XCD-aware bijective chunked swizzle; s_setprio(1) around MFMA cluster.
//  - Operand layout: col/row = lane&31, k = (lane>>5)*8+e.
//    C/D: px = lane&31, co = (reg&3) + 8*(reg>>2) + 4*(lane>>5).
// mids: NCG=4, PY=1 -> grid 512 = 2/CU.  final: NCG=16, PY=2 -> 1024 = 4/CU.
// ---------------------------------------------------------------------------
template <int NCG, int PY, bool FINAL>
__global__ __launch_bounds__(256) void conv_mfma_k(
    const f16* __restrict__ act, const f16* __restrict__ wb,
    const float* __restrict__ bias, f16* __restrict__ out) {
  constexpr int PX = 32;
  constexpr int XB = HW / PX;
  constexpr int LPW = PX + 2;
  constexpr int GEOM = (HW / PY) * XB;
  constexpr int NB = FINAL ? GEOM * 4 : GEOM;
  __shared__ f16 ldsB[(PY + 2) * LPW * 128];
  f16x8* ldsB8 = (f16x8*)ldsB;
  const f16x8* actF8 = (const f16x8*)act;
  const f16x8* wbF8 = (const f16x8*)wb;

  const int tid = threadIdx.x;
  const int l = tid & 63;
  const int w = tid >> 6;
  const int lc = l & 31;       // col lane (px / co)
  const int lh = l >> 5;       // k-half

  // XCD-aware bijective swizzle of the linear block id
  const int lid = blockIdx.x;
  const int l2 = (lid & 7) * (NB >> 3) + (lid >> 3);
  const int cfq = FINAL ? (l2 / GEOM) : 0;
  const int rem = l2 % GEOM;
  const int y0 = (rem / XB) * PY;
  const int x0 = (rem % XB) * PX;
  const int cgw = (FINAL ? cfq * 4 : 0) + w;  // wave's co-group

  // ---- stage B tile: halo rows y0..y0+PY+1, cols x0..x0+33, swizzled ----
  constexpr int NCH = (PY + 2) * LPW * 16;
#pragma unroll
  for (int it = 0; it < (NCH + 255) / 256; it++) {
    int cid = it * 256 + tid;
    if (cid < NCH) {
      int row = cid / (LPW * 16);
      int rem2 = cid - row * (LPW * 16);
      int lp = rem2 >> 4;
      int c = rem2 & 15;
      f16x8 v = actF8[((y0 + row) * HB + x0 + lp) * 16 + (c ^ (lp & 7))];
      ldsB8[(row * LPW + lp) * 16 + c] = v;
    }
  }

  // ---- prologue: A(0) into register buffer 0 (overlaps B staging) ----
  f16x8 af[2][8];
#pragma unroll
  for (int kc = 0; kc < 8; kc++)
    af[0][kc] = wbF8[((0 * NCG + cgw) * 8 + kc) * 64 + l];

  __syncthreads();

  f32x16 acc[PY];
#pragma unroll
  for (int rr = 0; rr < PY; rr++)
#pragma unroll
    for (int j = 0; j < 16; j++) acc[rr][j] = 0.f;

#pragma unroll
  for (int t = 0; t < 9; t++) {
    // issue next tap's A loads into the other register buffer
    if (t < 8) {
#pragma unroll
      for (int kc = 0; kc < 8; kc++)
        af[(t + 1) & 1][kc] = wbF8[(((t + 1) * NCG + cgw) * 8 + kc) * 64 + l];
    }
    // compute tap t (MFMA cluster under raised priority)
    const int dx = t - (t / 3) * 3, r = t / 3;
    const int lp = lc + dx;
    __builtin_amdgcn_s_setprio(1);
#pragma unroll
    for (int kc = 0; kc < 8; kc++) {
      const int c = kc * 2 + lh;
      f16x8 fb[PY];
#pragma unroll
      for (int rr = 0; rr < PY; rr++)
        fb[rr] = ldsB8[((r + rr) * LPW + lp) * 16 + (c ^ (lp & 7))];
#pragma unroll
      for (int rr = 0; rr < PY; rr++)
        acc[rr] = __builtin_amdgcn_mfma_f32_32x32x16_f16(
            af[t & 1][kc], fb[rr], acc[rr], 0, 0, 0);
    }
    __builtin_amdgcn_s_setprio(0);
  }

  // ---- epilogue: C/D px = lc, co = (j&3) + 8*(j>>2) + 4*lh ----
#pragma unroll
  for (int rr = 0; rr < PY; rr++) {
    const int px = x0 + lc;
    const int yy = y0 + rr;
#pragma unroll
    for (int q = 0; q < 4; q++) {
      int co = cgw * 32 + 8 * q + 4 * lh;
      if (FINAL && co >= 448) continue;
      f16x4 sv;
#pragma unroll
      for (int j = 0; j < 4; j++) {
        float v;
        if (FINAL) {
          // pad logit channels 441..447: -inf-ish so softmax ignores them
          v = (co + j < 441) ? acc[rr][q * 4 + j] + bias[co + j] : -60000.f;
        } else {
          float bv = (co + j < 100) ? bias[co + j] : 0.f;
          v = acc[rr][q * 4 + j] + bv;
          v = v > 0.f ? v : 0.01f * v;
        }
        sv[j] = (f16)v;
      }
      f16* op = FINAL ? out + (yy * HW + px) * 448 + co
                      : out + ((yy + 1) * HB + (px + 1)) * 128 + co;
      *(f16x4*)op = sv;
    }
  }
}

// ---------------------------------------------------------------------------
// fused softmax + WLS + solve, packed-f32 accumulation, 32 threads/pixel
// (14 interleaved taps each: k = part + 32*j). grid = NPIX/8 = 2048 blocks
// -> 8 blocks/CU for latency hiding on the itp gathers.
// itp: [ITW*ITW][16] f32 halo. logits: [NPIX][448] f16 (441..447 = -60000).
// ---------------------------------------------------------------------------
__global__ __launch_bounds__(256) void wls_k(
    const float* __restrict__ itp, const f16* __restrict__ logits,
    float* __restrict__ out) {
  const int tid = threadIdx.x;
  const int part = tid & 31;
  const int p = blockIdx.x * 8 + (tid >> 5);
  const int x = p & (HW - 1), y = p >> 7;
  const int hpc = (y + 10) * ITW + (x + 10);

  // padded-triangle row layout: row i covers cols (i&~1)..7 in pairs
  constexpr int roff[8] = {0, 4, 8, 11, 14, 16, 18, 19};
  constexpr int rnp[8] = {4, 4, 3, 3, 2, 2, 1, 1};

  // preload 14 logits: k = part + 32*j
  const f16* lp = logits + p * 448 + part;
  f16 lgv[14];
#pragma unroll
  for (int j = 0; j < 14; j++) lgv[j] = lp[j * 32];

  float m = -1e30f;
#pragma unroll
  for (int j = 0; j < 14; j++) m = fmaxf(m, (float)lgv[j]);
  m = fmaxf(m, __shfl_xor(m, 1));
  m = fmaxf(m, __shfl_xor(m, 2));
  m = fmaxf(m, __shfl_xor(m, 4));
  m = fmaxf(m, __shfl_xor(m, 8));
  m = fmaxf(m, __shfl_xor(m, 16));

  f32x2 A2[20];
#pragma unroll
  for (int i = 0; i < 20; i++) A2[i] = f32x2{0.f, 0.f};
  f32x2 Bm2[12];  // [c][rowpair]
#pragma unroll
  for (int i = 0; i < 12; i++) Bm2[i] = f32x2{0.f, 0.f};
  float S = 0.f;

#pragma unroll
  for (int j = 0; j < 14; j++) {
    const int k = part + 32 * j;
    const float u = __expf((float)lgv[j] - m);
    S += u;
    if (k < 441) {
      const int ky = k / 21;
      const int kx = k - ky * 21;
      const float4* q =
          (const float4*)(itp + (hpc + (ky - 10) * ITW + (kx - 10)) * 16);
      float4 f0 = q[0], f1 = q[1], f2 = q[2];
      f32x2 xv2[4] = {{f0.x, f1.x}, {f1.y, f1.z}, {f1.w, f2.x}, {f2.y, f2.z}};
      f32x2 ux2[4];
#pragma unroll
      for (int rp = 0; rp < 4; rp++) ux2[rp] = u * xv2[rp];
#pragma unroll
      for (int i = 0; i < 8; i++) {
        const float uxi = ux2[i >> 1][i & 1];
        const f32x2 sp = {uxi, uxi};
        const int b2 = (i & ~1) >> 1;
#pragma unroll
        for (int pj = 0; pj < 4; pj++) {
          if (pj < rnp[i]) A2[roff[i] + pj] = sp * xv2[b2 + pj] + A2[roff[i] + pj];
        }
      }
      const float yv[3] = {f0.y, f0.z, f0.w};
#pragma unroll
      for (int c = 0; c < 3; c++) {
        const f32x2 ys = {yv[c], yv[c]};
#pragma unroll
        for (int rp = 0; rp < 4; rp++)
          Bm2[c * 4 + rp] = ys * ux2[rp] + Bm2[c * 4 + rp];
      }
    }
  }

  // cross-part reduction (32 lanes per pixel), 64-bit shuffles
#pragma unroll
  for (int i = 0; i < 20; i++) {
    A2[i] += shflx2(A2[i], 1);
    A2[i] += shflx2(A2[i], 2);
    A2[i] += shflx2(A2[i], 4);
    A2[i] += shflx2(A2[i], 8);
    A2[i] += shflx2(A2[i], 16);
  }
#pragma unroll
  for (int i = 0; i < 12; i++) {
    Bm2[i] += shflx2(Bm2[i], 1);
    Bm2[i] += shflx2(Bm2[i], 2);
    Bm2[i] += shflx2(Bm2[i], 4);
    Bm2[i] += shflx2(Bm2[i], 8);
    Bm2[i] += shflx2(Bm2[i], 16);
  }
  S += __shfl_xor(S, 1);
  S += __shfl_xor(S, 2);
  S += __shfl_xor(S, 4);
  S += __shfl_xor(S, 8);
  S += __shfl_xor(S, 16);

  // unpack to full 8x8 + 3 RHS
  float M[8][8], R[8][3];
#pragma unroll
  for (int i = 0; i < 8; i++) {
#pragma unroll
    for (int j = 0; j < 8; j++) {
      const int lo = (i < j) ? i : j;
      const int hi = (i < j) ? j : i;
      const int d = hi - (lo & ~1);
      M[i][j] = A2[roff[lo] + (d >> 1)][d & 1];
    }
#pragma unroll
    for (int c = 0; c < 3; c++) R[i][c] = Bm2[c * 4 + (i >> 1)][i & 1];
  }
#pragma unroll
  for (int i = 1; i < 8; i++) M[i][i] += S * EPS;

  // Gaussian elimination (SPD, no pivot), redundant across lanes
#pragma unroll
  for (int c = 0; c < 8; c++) {
    const float inv = 1.f / M[c][c];
#pragma unroll
    for (int r = c + 1; r < 8; r++) {
      const float f = M[r][c] * inv;
#pragma unroll
      for (int j = c + 1; j < 8; j++) M[r][j] = fmaf(-f, M[c][j], M[r][j]);
#pragma unroll
      for (int cc = 0; cc < 3; cc++) R[r][cc] = fmaf(-f, R[c][cc], R[r][cc]);
    }
  }
  float para[8][3];
#pragma unroll
  for (int r = 7; r >= 0; r--) {
#pragma unroll
    for (int cc = 0; cc < 3; cc++) {
      float s = R[r][cc];
#pragma unroll
      for (int j = r + 1; j < 8; j++) s = fmaf(-M[r][j], para[j][cc], s);
      para[r][cc] = s / M[r][r];
    }
  }

  const float4* qc = (const float4*)(itp + hpc * 16);
  float4 c1 = qc[1], c2 = qc[2];
  float dv[8] = {1.f, c1.x, c1.y, c1.z, c1.w, c2.x, c2.y, c2.z};
  if (part < 3) {
    float res = 0.f;
#pragma unroll
    for (int i = 0; i < 8; i++) res = fmaf(dv[i], para[i][part], res);
    out[part * NPIX + p] = res;
  }
}

// ---------------------------------------------------------------------------
extern "C" void kernel_launch(void* const* d_in, const int* in_sizes, int n_in,
                              void* d_out, int out_size, void* d_ws, size_t ws_size,
                              hipStream_t stream) {
  const float* input = (const float*)d_in[0];
  const float* w0 = (const float*)d_in[2];
  const float* b0 = (const float*)d_in[3];
  const float* wmid = (const float*)d_in[4];
  const float* bmid = (const float*)d_in[5];
  const float* wfin = (const float*)d_in[6];
  const float* bfin = (const float*)d_in[7];
  float* out = (float*)d_out;

  f16* act0 = (f16*)d_ws;                           // HPIX*128
  f16* act1 = act0 + HPIX * 128;                    // HPIX*128
  f16* logits = act1 + HPIX * 128;                  // NPIX*448
  f16* wbuf = logits + NPIX * 448;                  // 23*9*16384
  f16* wfbuf = wbuf + 23 * 9 * 16384;               // 9*65536
  float* inputT = (float*)(wfbuf + 9 * 65536);      // 148*148*16

  // zero both act buffers (halo + pad channels)
  {
    int n = (2 * HPIX * 128 * 2) / 16;
    zero_buf<<<(n + 255) / 256, 256, 0, stream>>>((i32x4*)act0, n);
  }
  prep_input_k<<<(ITW * ITW + 255) / 256, 256, 0, stream>>>(input, inputT);
  pack_wmid_k<<<(23 * 9 * 16384) / 256, 256, 0, stream>>>(wmid, wbuf);
  pack_wfin_k<<<(9 * 65536) / 256, 256, 0, stream>>>(wfin, wfbuf);

  conv0_k<<<dim3(8, 8, 8), 256, 0, stream>>>(input, w0, b0, act0);

  // mids: 32x32 MFMA, PX32 x PY1, 4 cg/block -> grid 512 = 2/CU
  for (int L = 0; L < 23; L++) {
    const f16* src = (L & 1) ? act1 : act0;
    f16* dst = (L & 1) ? act0 : act1;
    conv_mfma_k<4, 1, false><<<dim3(512), 256, 0, stream>>>(
        src, wbuf + (long)L * 9 * 16384, bmid + L * 100, dst);
  }
  // final: 32x32 MFMA, PX32 x PY2, 4 cfq x 4 cg -> grid 1024 = 4/CU
  conv_mfma_k<16, 2, true><<<dim3(1024), 256, 0, stream>>>(
      act1, wfbuf, bfin, logits);

  wls_k<<<NPIX / 8, 256, 0, stream>>>(inputT, logits, out);
}

// Round 16
// 327.758 us; speedup vs baseline: 1.1126x; 1.1126x over previous
//
#include <hip/hip_runtime.h>
#include <hip/hip_bf16.h>

#define HW 128
#define NPIX (HW * HW)
#define HB 130            // halo-padded activation image width
#define HPIX (HB * HB)
#define ITW 148           // halo-padded transposed-input width (halo 10)
#define EPS 1e-4f

typedef __attribute__((ext_vector_type(4))) float f32x4;
typedef __attribute__((ext_vector_type(2))) float f32x2;
typedef _Float16 f16;
typedef __attribute__((ext_vector_type(8))) _Float16 f16x8;
typedef __attribute__((ext_vector_type(4))) _Float16 f16x4;
typedef __attribute__((ext_vector_type(4))) int i32x4;

__device__ __forceinline__ f32x2 shflx2(f32x2 v, int m) {
  double d = __builtin_bit_cast(double, v);
  d = __shfl_xor(d, m);
  return __builtin_bit_cast(f32x2, d);
}

// ---------------------------------------------------------------------------
__global__ __launch_bounds__(256) void zero_buf(i32x4* __restrict__ p, int n) {
  int i = blockIdx.x * 256 + threadIdx.x;
  if (i < n) p[i] = i32x4{0, 0, 0, 0};
}

// ---------------------------------------------------------------------------
// transpose input NCHW fp32 -> halo-padded [148*148][16] fp32
// ch0 = validity/ones, ch1..3 = input[0..2], ch4..10 = input[3..9], rest 0
// ---------------------------------------------------------------------------
__global__ __launch_bounds__(256) void prep_input_k(
    const float* __restrict__ in, float* __restrict__ itp) {
  int idx = blockIdx.x * 256 + threadIdx.x;
  if (idx >= ITW * ITW) return;
  int py = idx / ITW, px = idx - py * ITW;
  float v[16];
#pragma unroll
  for (int i = 0; i < 16; i++) v[i] = 0.f;
  if (py >= 10 && py < 138 && px >= 10 && px < 138) {
    int p = (py - 10) * HW + (px - 10);
    v[0] = 1.f;
#pragma unroll
    for (int c = 0; c < 10; c++) v[1 + c] = in[c * NPIX + p];
  }
  float4* op = (float4*)(itp + idx * 16);
#pragma unroll
  for (int g = 0; g < 4; g++)
    op[g] = make_float4(v[g * 4], v[g * 4 + 1], v[g * 4 + 2], v[g * 4 + 3]);
}

// ---------------------------------------------------------------------------
// weight repack to MFMA-fragment-major order:
//   wb[L][t][cf][kc][lane][e]  (f16), co = cf*16 + (lane&15),
//   ci = kc*32 + (lane>>4)*8 + e  -> one wave A-frag load = contiguous 1KB.
// ---------------------------------------------------------------------------
__global__ __launch_bounds__(256) void pack_wmid_k(
    const float* __restrict__ wm, f16* __restrict__ wb) {
  int idx = blockIdx.x * 256 + threadIdx.x;  // 23*9*16384
  int e = idx & 7;
  int l = (idx >> 3) & 63;
  int kc = (idx >> 9) & 3;
  int cf = (idx >> 11) & 7;
  int tL = idx >> 14;
  int L = tL / 9;
  int t = tL - L * 9;
  int co = cf * 16 + (l & 15);
  int ci = kc * 32 + (l >> 4) * 8 + e;
  float v = 0.f;
  if (co < 100 && ci < 100) v = wm[((L * 100 + co) * 100 + ci) * 9 + t];
  wb[idx] = (f16)v;
}

// wfin [441][100][3][3] f32 -> [9][32cf][4kc][64][8]  (co padded to 512)
__global__ __launch_bounds__(256) void pack_wfin_k(
    const float* __restrict__ wf, f16* __restrict__ wb) {
  int idx = blockIdx.x * 256 + threadIdx.x;  // 9*65536
  int e = idx & 7;
  int l = (idx >> 3) & 63;
  int kc = (idx >> 9) & 3;
  int cf = (idx >> 11) & 31;
  int t = idx >> 16;
  int co = cf * 16 + (l & 15);
  int ci = kc * 32 + (l >> 4) * 8 + e;
  float v = 0.f;
  if (co < 441 && ci < 100) v = wf[(co * 100 + ci) * 9 + t];
  wb[idx] = (f16)v;
}

// ---------------------------------------------------------------------------
// conv0: 10 -> 100 direct fp32, write f16 halo NHWC [HPIX][128]
// ---------------------------------------------------------------------------
__global__ __launch_bounds__(256) void conv0_k(
    const float* __restrict__ in, const float* __restrict__ w0,
    const float* __restrict__ b0, f16* __restrict__ act) {
  const int tx = threadIdx.x & 15, ty = threadIdx.x >> 4;
  const int x = blockIdx.x * 16 + tx, y = blockIdx.y * 16 + ty;
  const int co0 = blockIdx.z * 16;
  const int nco = max(0, min(16, 100 - co0));
  float acc[16];
#pragma unroll
  for (int i = 0; i < 16; i++) acc[i] = (i < nco) ? b0[co0 + i] : 0.f;
  for (int ci = 0; ci < 10; ci++) {
    const float* ip = in + ci * NPIX;
    float v[9];
#pragma unroll
    for (int t = 0; t < 9; t++) {
      int ny = y + t / 3 - 1, nx = x + t % 3 - 1;
      bool ok = ((unsigned)ny < (unsigned)HW) && ((unsigned)nx < (unsigned)HW);
      v[t] = ok ? ip[ny * HW + nx] : 0.f;
    }
    const float* wp = w0 + (co0 * 10 + ci) * 9;
#pragma unroll
    for (int i = 0; i < 16; i++) {
      if (i < nco) {
#pragma unroll
        for (int t = 0; t < 9; t++)
          acc[i] = fmaf(wp[i * 90 + t], v[t], acc[i]);
      }
    }
  }
  f16* op = act + ((y + 1) * HB + (x + 1)) * 128 + co0;
#pragma unroll
  for (int g = 0; g < 4; g++) {
    f16x4 sv;
#pragma unroll
    for (int j = 0; j < 4; j++) sv[j] = (f16)acc[g * 4 + j];
    *(f16x4*)(op + g * 4) = sv;
  }
}

// ---------------------------------------------------------------------------
// implicit-GEMM 3x3 conv, MFMA f16 16x16x32, PY row-block tiles,
// A-in-registers (measured-best R14 configuration).
//  - B in LDS [(PY+2)][PX+2][16ch] (XOR chunk swizzle), ONE barrier.
//  - A global->VGPR register dbuf af[2][MW][4], next tap issued early.
//  - XCD-aware bijective chunked swizzle; s_setprio(1) around MFMA cluster.
// mids: NCF=8, PX=16, PY=4, MW=1 -> grid (256, 2) = 512 = 2/CU, A 74 MB.
// final: NCF=32, PX=32, PY=4, MW=2 -> grid (512) = 2/CU, A 151 MB.
// ---------------------------------------------------------------------------
template <int NCF, int PX, int PY, int MW, bool FINAL>
__global__ __launch_bounds__(256) void conv_mfma_k(
    const f16* __restrict__ act, const f16* __restrict__ wb,
    const float* __restrict__ bias, f16* __restrict__ out) {
  constexpr int XB = HW / PX;
  constexpr int LPW = PX + 2;
  constexpr int NN = PX / 16;
  constexpr int GEOM = (HW / PY) * XB;
  constexpr int NB = FINAL ? GEOM * 4 : GEOM;
  __shared__ f16 ldsB[(PY + 2) * LPW * 128];
  f16x8* ldsB8 = (f16x8*)ldsB;
  const f16x8* actF8 = (const f16x8*)act;
  const f16x8* wbF8 = (const f16x8*)wb;

  const int tid = threadIdx.x;
  const int l = tid & 63;
  const int w = tid >> 6;
  const int lr = l & 15;
  const int lg = l >> 4;

  // XCD-aware bijective swizzle of the geometric block id
  const int lid = blockIdx.x;
  const int l2 = (lid & 7) * (NB >> 3) + (lid >> 3);
  const int cfq = FINAL ? (l2 / GEOM) : 0;
  const int rem = l2 % GEOM;
  const int y0 = (rem / XB) * PY;          // output row base
  const int x0 = (rem % XB) * PX;
  // block cf base: final packs quarter into x; mids use blockIdx.y halves
  const int cf0 = FINAL ? cfq * 8 : blockIdx.y * 4 * MW;
  const int cfw = cf0 + w * MW;            // wave's cf base

  // ---- stage B tile: halo rows y0..y0+PY+1, cols x0..x0+PX+1, swizzled ----
  constexpr int NCH = (PY + 2) * LPW * 16;
#pragma unroll
  for (int it = 0; it < (NCH + 255) / 256; it++) {
    int cid = it * 256 + tid;
    if (cid < NCH) {
      int row = cid / (LPW * 16);
      int rem2 = cid - row * (LPW * 16);
      int lp = rem2 >> 4;
      int c = rem2 & 15;
      f16x8 v = actF8[((y0 + row) * HB + x0 + lp) * 16 + (c ^ (lp & 7))];
      ldsB8[(row * LPW + lp) * 16 + c] = v;
    }
  }

  // ---- prologue: A(0) into register buffer 0 (overlaps B staging) ----
  f16x8 af[2][MW][4];
#pragma unroll
  for (int m = 0; m < MW; m++)
#pragma unroll
    for (int kc = 0; kc < 4; kc++)
      af[0][m][kc] = wbF8[((0 * NCF + cfw + m) * 4 + kc) * 64 + l];

  __syncthreads();

  f32x4 acc[MW][NN][PY];
#pragma unroll
  for (int m = 0; m < MW; m++)
#pragma unroll
    for (int n = 0; n < NN; n++)
#pragma unroll
      for (int rr = 0; rr < PY; rr++) acc[m][n][rr] = f32x4{0.f, 0.f, 0.f, 0.f};

#pragma unroll
  for (int t = 0; t < 9; t++) {
    // issue next tap's A loads into the other register buffer
    if (t < 8) {
#pragma unroll
      for (int m = 0; m < MW; m++)
#pragma unroll
        for (int kc = 0; kc < 4; kc++)
          af[(t + 1) & 1][m][kc] =
              wbF8[(((t + 1) * NCF + cfw + m) * 4 + kc) * 64 + l];
    }
    // compute tap t (MFMA cluster under raised priority)
    const int dx = t - (t / 3) * 3, r = t / 3;
    __builtin_amdgcn_s_setprio(1);
#pragma unroll
    for (int kc = 0; kc < 4; kc++) {
      const int kq = kc * 4 + lg;
      f16x8 fb[NN][PY];
#pragma unroll
      for (int n = 0; n < NN; n++)
#pragma unroll
        for (int rr = 0; rr < PY; rr++) {
          const int lp = lr + n * 16 + dx;
          fb[n][rr] = ldsB8[((r + rr) * LPW + lp) * 16 + (kq ^ (lp & 7))];
        }
#pragma unroll
      for (int m = 0; m < MW; m++)
#pragma unroll
        for (int n = 0; n < NN; n++)
#pragma unroll
          for (int rr = 0; rr < PY; rr++)
            acc[m][n][rr] = __builtin_amdgcn_mfma_f32_16x16x32_f16(
                af[t & 1][m][kc], fb[n][rr], acc[m][n][rr], 0, 0, 0);
    }
    __builtin_amdgcn_s_setprio(0);
  }

  // ---- epilogue ----
#pragma unroll
  for (int m = 0; m < MW; m++) {
#pragma unroll
    for (int n = 0; n < NN; n++) {
#pragma unroll
      for (int rr = 0; rr < PY; rr++) {
        int co = (cfw + m) * 16 + lg * 4;
        int px = x0 + n * 16 + lr;
        int yy = y0 + rr;
        if (FINAL && co >= 448) continue;
        f16x4 sv;
#pragma unroll
        for (int j = 0; j < 4; j++) {
          float v;
          if (FINAL) {
            // pad logit channels 441..447: -inf-ish so softmax ignores them
            v = (co + j < 441) ? acc[m][n][rr][j] + bias[co + j] : -60000.f;
          } else {
            float bv = (co + j < 100) ? bias[co + j] : 0.f;
            v = acc[m][n][rr][j] + bv;
            v = v > 0.f ? v : 0.01f * v;
          }
          sv[j] = (f16)v;
        }
        f16* op = FINAL ? out + (yy * HW + px) * 448 + co
                        : out + ((yy + 1) * HB + (px + 1)) * 128 + co;
        *(f16x4*)op = sv;
      }
    }
  }
}

// ---------------------------------------------------------------------------
// fused softmax + WLS + solve, packed-f32 (v_pk_fma_f32) accumulation.
// 16 threads/pixel, interleaved taps (k = part + 16*j) -> coalesced reads.
// A accumulated as padded-triangle pairs A2[20]; Bm as 12 row-pairs.
// itp: [ITW*ITW][16] f32 halo. logits: [NPIX][448] f16 (441..447 = -60000).
// grid = 1024 blocks.
// ---------------------------------------------------------------------------
__global__ __launch_bounds__(256) void wls_k(
    const float* __restrict__ itp, const f16* __restrict__ logits,
    float* __restrict__ out) {
  const int tid = threadIdx.x;
  const int part = tid & 15;
  const int p = blockIdx.x * 16 + (tid >> 4);
  const int x = p & (HW - 1), y = p >> 7;
  const int hpc = (y + 10) * ITW + (x + 10);

  // padded-triangle row layout: row i covers cols (i&~1)..7 in pairs
  constexpr int roff[8] = {0, 4, 8, 11, 14, 16, 18, 19};
  constexpr int rnp[8] = {4, 4, 3, 3, 2, 2, 1, 1};

  // preload 28 logits: k = part + 16*j
  const f16* lp = logits + p * 448 + part;
  f16 lgv[28];
#pragma unroll
  for (int j = 0; j < 28; j++) lgv[j] = lp[j * 16];

  float m = -1e30f;
#pragma unroll
  for (int j = 0; j < 28; j++) m = fmaxf(m, (float)lgv[j]);
  m = fmaxf(m, __shfl_xor(m, 1));
  m = fmaxf(m, __shfl_xor(m, 2));
  m = fmaxf(m, __shfl_xor(m, 4));
  m = fmaxf(m, __shfl_xor(m, 8));

  f32x2 A2[20];
#pragma unroll
  for (int i = 0; i < 20; i++) A2[i] = f32x2{0.f, 0.f};
  f32x2 Bm2[12];  // [c][rowpair]
#pragma unroll
  for (int i = 0; i < 12; i++) Bm2[i] = f32x2{0.f, 0.f};
  float S = 0.f;

  int ky = 0, kx = part;  // k = part + 16*j = 21*ky + kx
#pragma unroll
  for (int j = 0; j < 28; j++) {
    const int k = part + 16 * j;
    const float u = __expf((float)lgv[j] - m);
    S += u;
    if (k < 441) {
      const float4* q =
          (const float4*)(itp + (hpc + (ky - 10) * ITW + (kx - 10)) * 16);
      float4 f0 = q[0], f1 = q[1], f2 = q[2];
      f32x2 xv2[4] = {{f0.x, f1.x}, {f1.y, f1.z}, {f1.w, f2.x}, {f2.y, f2.z}};
      f32x2 ux2[4];
#pragma unroll
      for (int rp = 0; rp < 4; rp++) ux2[rp] = u * xv2[rp];
#pragma unroll
      for (int i = 0; i < 8; i++) {
        const float uxi = ux2[i >> 1][i & 1];
        const f32x2 sp = {uxi, uxi};
        const int b2 = (i & ~1) >> 1;
#pragma unroll
        for (int pj = 0; pj < 4; pj++) {
          if (pj < rnp[i]) A2[roff[i] + pj] = sp * xv2[b2 + pj] + A2[roff[i] + pj];
        }
      }
      const float yv[3] = {f0.y, f0.z, f0.w};
#pragma unroll
      for (int c = 0; c < 3; c++) {
        const f32x2 ys = {yv[c], yv[c]};
#pragma unroll
        for (int rp = 0; rp < 4; rp++)
          Bm2[c * 4 + rp] = ys * ux2[rp] + Bm2[c * 4 + rp];
      }
    }
    kx += 16;
    if (kx >= 21) { kx -= 21; ky += 1; }
  }

  // cross-part reduction (16 lanes per pixel), 64-bit shuffles
#pragma unroll
  for (int i = 0; i < 20; i++) {
    A2[i] += shflx2(A2[i], 1);
    A2[i] += shflx2(A2[i], 2);
    A2[i] += shflx2(A2[i], 4);
    A2[i] += shflx2(A2[i], 8);
  }
#pragma unroll
  for (int i = 0; i < 12; i++) {
    Bm2[i] += shflx2(Bm2[i], 1);
    Bm2[i] += shflx2(Bm2[i], 2);
    Bm2[i] += shflx2(Bm2[i], 4);
    Bm2[i] += shflx2(Bm2[i], 8);
  }
  S += __shfl_xor(S, 1);
  S += __shfl_xor(S, 2);
  S += __shfl_xor(S, 4);
  S += __shfl_xor(S, 8);

  // unpack to full 8x8 + 3 RHS
  float M[8][8], R[8][3];
#pragma unroll
  for (int i = 0; i < 8; i++) {
#pragma unroll
    for (int j = 0; j < 8; j++) {
      const int lo = (i < j) ? i : j;
      const int hi = (i < j) ? j : i;
      const int d = hi - (lo & ~1);
      M[i][j] = A2[roff[lo] + (d >> 1)][d & 1];
    }
#pragma unroll
    for (int c = 0; c < 3; c++) R[i][c] = Bm2[c * 4 + (i >> 1)][i & 1];
  }
#pragma unroll
  for (int i = 1; i < 8; i++) M[i][i] += S * EPS;

  // Gaussian elimination (SPD, no pivot), redundant across lanes
#pragma unroll
  for (int c = 0; c < 8; c++) {
    const float inv = 1.f / M[c][c];
#pragma unroll
    for (int r = c + 1; r < 8; r++) {
      const float f = M[r][c] * inv;
#pragma unroll
      for (int j = c + 1; j < 8; j++) M[r][j] = fmaf(-f, M[c][j], M[r][j]);
#pragma unroll
      for (int cc = 0; cc < 3; cc++) R[r][cc] = fmaf(-f, R[c][cc], R[r][cc]);
    }
  }
  float para[8][3];
#pragma unroll
  for (int r = 7; r >= 0; r--) {
#pragma unroll
    for (int cc = 0; cc < 3; cc++) {
      float s = R[r][cc];
#pragma unroll
      for (int j = r + 1; j < 8; j++) s = fmaf(-M[r][j], para[j][cc], s);
      para[r][cc] = s / M[r][r];
    }
  }

  const float4* qc = (const float4*)(itp + hpc * 16);
  float4 c1 = qc[1], c2 = qc[2];
  float dv[8] = {1.f, c1.x, c1.y, c1.z, c1.w, c2.x, c2.y, c2.z};
  if (part < 3) {
    float res = 0.f;
#pragma unroll
    for (int i = 0; i < 8; i++) res = fmaf(dv[i], para[i][part], res);
    out[part * NPIX + p] = res;
  }
}

// ---------------------------------------------------------------------------
extern "C" void kernel_launch(void* const* d_in, const int* in_sizes, int n_in,
                              void* d_out, int out_size, void* d_ws, size_t ws_size,
                              hipStream_t stream) {
  const float* input = (const float*)d_in[0];
  const float* w0 = (const float*)d_in[2];
  const float* b0 = (const float*)d_in[3];
  const float* wmid = (const float*)d_in[4];
  const float* bmid = (const float*)d_in[5];
  const float* wfin = (const float*)d_in[6];
  const float* bfin = (const float*)d_in[7];
  float* out = (float*)d_out;

  f16* act0 = (f16*)d_ws;                           // HPIX*128
  f16* act1 = act0 + HPIX * 128;                    // HPIX*128
  f16* logits = act1 + HPIX * 128;                  // NPIX*448
  f16* wbuf = logits + NPIX * 448;                  // 23*9*16384
  f16* wfbuf = wbuf + 23 * 9 * 16384;               // 9*65536
  float* inputT = (float*)(wfbuf + 9 * 65536);      // 148*148*16

  // zero both act buffers (halo + pad channels)
  {
    int n = (2 * HPIX * 128 * 2) / 16;
    zero_buf<<<(n + 255) / 256, 256, 0, stream>>>((i32x4*)act0, n);
  }
  prep_input_k<<<(ITW * ITW + 255) / 256, 256, 0, stream>>>(input, inputT);
  pack_wmid_k<<<(23 * 9 * 16384) / 256, 256, 0, stream>>>(wmid, wbuf);
  pack_wfin_k<<<(9 * 65536) / 256, 256, 0, stream>>>(wfin, wfbuf);

  conv0_k<<<dim3(8, 8, 8), 256, 0, stream>>>(input, w0, b0, act0);

  // mids: px16 x py4, cf-split MW=1 -> grid (256, 2) = 512 = 2/CU, A 74 MB
  for (int L = 0; L < 23; L++) {
    const f16* src = (L & 1) ? act1 : act0;
    f16* dst = (L & 1) ? act0 : act1;
    conv_mfma_k<8, 16, 4, 1, false><<<dim3(256, 2), 256, 0, stream>>>(
        src, wbuf + (long)L * 9 * 16384, bmid + L * 100, dst);
  }
  // final: px32 x py4, MW=2, cfq packed in x -> grid 512 = 2/CU, A 151 MB
  conv_mfma_k<32, 32, 4, 2, true><<<dim3(512), 256, 0, stream>>>(
      act1, wfbuf, bfin, logits);

  wls_k<<<NPIX * 16 / 256, 256, 0, stream>>>(inputT, logits, out);
}